// Round 5
// baseline (4773.934 us; speedup 1.0000x reference)
//
#include <hip/hip_runtime.h>
#include <math.h>

// Problem constants
#define S_    32
#define U_    10
#define B_    320           // S*U sequences
#define T_    120
#define NMEL_ 40
#define H_    768
#define G4_   3072          // 4*H gates
#define D_    256
#define XP_   64            // mel features zero-padded 40 -> 64
#define K0_   (XP_ + H_)    // 832, layer-0 fused K
#define K12_  (2 * H_)      // 1536, layers 1/2 fused K
#define NP_   4             // h-buffer parities (staleness window for leader-inv)

#define NB0   48            // layer-0 blocks (16 units each)
#define NB12  96            // layer-1/2 blocks (8 units each)
#define NBLK  (NB0 + 2 * NB12)  // 240 blocks, 1 per CU

// LDS: weights only (A is staged in VGPRs via inline-asm prefetch ring).
// layer 0: 26*64*64 = 106,496 ; layers 1/2: 48*32*64 = 98,304
#define SMEM_BYTES 106496

typedef _Float16 half8 __attribute__((ext_vector_type(8)));
typedef float floatx4 __attribute__((ext_vector_type(4)));

__device__ __forceinline__ float sigm(float x) {
  return 1.f / (1.f + __expf(-x));
}
__device__ __forceinline__ float tanh_f(float x) {
  x = fminf(15.f, fmaxf(-15.f, x));
  float e = __expf(2.f * x);
  return (e - 1.f) / (e + 1.f);
}

// s_waitcnt vmcnt(N) only (expcnt/lgkmcnt all-ones = no wait)
template <int N>
__device__ __forceinline__ void waitvm() {
  __builtin_amdgcn_s_waitcnt(0x3FF0 | (N & 0xF) | ((N >> 4) << 14));
}

// inline-asm 16B global load to VGPRs. volatile => issue order preserved and
// the compiler cannot collapse the prefetch depth (the R3 failure mode).
// SC0 bypasses the CU-private L1 (required for h freshness under leader-only
// L2 invalidation). The compiler does NOT auto-wait on asm loads; we count
// vmcnt by hand exactly like the verified LDS-DMA ring.
template <bool SC0>
__device__ __forceinline__ half8 aload(const _Float16* p) {
  half8 d;
  if constexpr (SC0)
    asm volatile("global_load_dwordx4 %0, %1, off sc0" : "=v"(d) : "v"(p));
  else
    asm volatile("global_load_dwordx4 %0, %1, off" : "=v"(d) : "v"(p));
  return d;
}

// ---------------- prep kernels ----------------

__global__ void prep_x0(const float* __restrict__ mel, _Float16* __restrict__ x0) {
  int idx = blockIdx.x * 256 + threadIdx.x;
  if (idx >= B_ * T_ * XP_) return;
  int k = idx & (XP_ - 1);
  int t = (idx >> 6) % T_;
  int b = idx / (XP_ * T_);
  float v = (k < NMEL_) ? mel[((size_t)b * NMEL_ + k) * T_ + t] : 0.f;
  x0[idx] = (_Float16)v;
}

__global__ void prep_w0(const float* __restrict__ Wih, const float* __restrict__ Whh,
                        _Float16* __restrict__ Wc) {
  int idx = blockIdx.x * 256 + threadIdx.x;
  if (idx >= G4_ * K0_) return;
  int k = idx % K0_;
  int n = idx / K0_;
  float v = 0.f;
  if (k < NMEL_)      v = Wih[(size_t)n * NMEL_ + k];
  else if (k >= XP_)  v = Whh[(size_t)n * H_ + (k - XP_)];
  Wc[idx] = (_Float16)v;
}

__global__ void prep_w12(const float* __restrict__ Wih, const float* __restrict__ Whh,
                         _Float16* __restrict__ Wc) {
  int idx = blockIdx.x * 256 + threadIdx.x;
  if (idx >= G4_ * K12_) return;
  int k = idx % K12_;
  int n = idx / K12_;
  float v = (k < H_) ? Wih[(size_t)n * H_ + k] : Whh[(size_t)n * H_ + (k - H_)];
  Wc[idx] = (_Float16)v;
}

__global__ void prep_bias(const float* __restrict__ bih, const float* __restrict__ bhh,
                          float* __restrict__ bias) {
  int idx = blockIdx.x * 256 + threadIdx.x;
  if (idx < G4_) bias[idx] = bih[idx] + bhh[idx];
}

// ---------------- persistent LSTM ----------------

// Per-block completion slots: fl[((s*3)+lp)*96 + blk]; release-stored 1 when
// block blk of layer lp finished grid-step s. Wave-parallel polling (any wave).
__device__ __forceinline__ void wait_group(int* fl, int sp, int lp, int lane) {
  if (lp < 0 || lp > 2) return;
  if (sp < lp || sp > lp + T_ - 1) return;
  const int tgt = (lp == 0) ? NB0 : NB12;
  const int base = (sp * 3 + lp) * 96;
  int spin = 0;
  for (;;) {
    int v0 = (lane < tgt)
                 ? __hip_atomic_load(&fl[base + lane], __ATOMIC_RELAXED,
                                     __HIP_MEMORY_SCOPE_AGENT) : 1;
    int v1 = (lane + 64 < tgt)
                 ? __hip_atomic_load(&fl[base + 64 + lane], __ATOMIC_RELAXED,
                                     __HIP_MEMORY_SCOPE_AGENT) : 1;
    if (__all(v0 != 0 && v1 != 0)) break;
    __builtin_amdgcn_s_sleep(1);
    if (++spin > 2000000) break;     // bounded: fail as absmax, not hang
  }
}

// One K-phase with a depth-D VGPR prefetch ring (inline-asm loads, hand
// counted vmcnt). A-fragment loads straight from global into the MFMA layout
// (row = m0+(lane&15), k-sub = (lane>>4)*8). W from LDS (XOR-swizzled).
// vmcnt discipline: chunk c landed after waiting to 2*min(DD-1, NC-1-c).
template <int NT, int D, int NC, bool SC0>
__device__ __forceinline__ void gemm_phase(
    const _Float16* __restrict__ lwW, int wchunk0,
    const _Float16* __restrict__ src, int strideE,
    int m0, int lane, floatx4 (&acc)[2][NT]) {
  const int lr = lane & 15, quad = lane >> 4;
  const _Float16* a0p = src + (size_t)(m0 + lr) * strideE + quad * 8;
  const _Float16* a1p = a0p + (size_t)16 * strideE;

  constexpr int DD = (D < NC) ? D : NC;
  half8 abuf[DD][2];
#pragma unroll
  for (int p = 0; p < DD; ++p) {
    abuf[p][0] = aload<SC0>(a0p + (size_t)p * 32);
    abuf[p][1] = aload<SC0>(a1p + (size_t)p * 32);
  }

  const int asw = (quad ^ ((lr >> 1) & 3)) * 8;    // swizzled LDS quarter for W

#pragma unroll
  for (int c = 0; c < NC; ++c) {
    const int rem = NC - 1 - c;                    // chunks issued after c
    if (rem >= DD - 1)        waitvm<2 * (DD - 1)>();
    else if (rem == 3)        waitvm<6>();
    else if (rem == 2)        waitvm<4>();
    else if (rem == 1)        waitvm<2>();
    else                      waitvm<0>();
    __builtin_amdgcn_sched_barrier(0);             // MFMA must not hoist (rule 18)
    half8 a0 = abuf[c % DD][0];
    half8 a1 = abuf[c % DD][1];
    half8 bf[NT];
#pragma unroll
    for (int nt = 0; nt < NT; ++nt)
      bf[nt] = *(const half8*)(lwW +
               ((size_t)((wchunk0 + c) * NT * 16 + nt * 16 + lr) * 32 + asw));
#pragma unroll
    for (int nt = 0; nt < NT; ++nt) {
      acc[0][nt] = __builtin_amdgcn_mfma_f32_16x16x32_f16(a0, bf[nt], acc[0][nt], 0, 0, 0);
      acc[1][nt] = __builtin_amdgcn_mfma_f32_16x16x32_f16(a1, bf[nt], acc[1][nt], 0, 0, 0);
    }
    if (c + DD < NC) {
      abuf[c % DD][0] = aload<SC0>(a0p + (size_t)(c + DD) * 32);
      abuf[c % DD][1] = aload<SC0>(a1p + (size_t)(c + DD) * 32);
    }
  }
}

__global__ __launch_bounds__(640, 3)
void lstm_persist(const _Float16* __restrict__ x0,
                  const _Float16* __restrict__ Wc0, const _Float16* __restrict__ Wc1,
                  const _Float16* __restrict__ Wc2,
                  const float* __restrict__ bias, _Float16* __restrict__ hbuf,
                  int* __restrict__ flags, int* __restrict__ tick,
                  int* __restrict__ leadDone) {
  extern __shared__ _Float16 lw[];
  const int bid = blockIdx.x;

  int layer, tile, units, K;
  const _Float16* Wsrc;
  if (bid < NB0)            { layer = 0; tile = bid;              units = 16; K = K0_;  Wsrc = Wc0; }
  else if (bid < NB0+NB12)  { layer = 1; tile = bid - NB0;        units = 8;  K = K12_; Wsrc = Wc1; }
  else                      { layer = 2; tile = bid - NB0 - NB12; units = 8;  K = K12_; Wsrc = Wc2; }
  const int nrows = units * 4;
  const int j0 = tile * units;

  unsigned xcc;
  asm volatile("s_getreg_b32 %0, hwreg(HW_REG_XCC_ID)" : "=s"(xcc));
  xcc &= 7;

  // one-time: stage weight slice into LDS, chunk-major + XOR-swizzled quarters
  {
    const int total = (K / 32) * nrows * 4;
    for (int idx = threadIdx.x; idx < total; idx += 640) {
      int c = idx / (nrows * 4);
      int rem = idx % (nrows * 4);
      int r = rem >> 2;
      int q = rem & 3;
      int grow = (r / units) * H_ + j0 + (r % units);
      half8 v = *(const half8*)(Wsrc + (size_t)grow * K + c * 32 + q * 8);
      int qs = q ^ ((r >> 1) & 3);
      *(half8*)(lw + ((size_t)(c * nrows + r) * 32 + qs * 8)) = v;
    }
  }
  __syncthreads();

  const int lane = threadIdx.x & 63;
  const int wv = threadIdx.x >> 6;      // 10 waves
  const int lr = lane & 15;
  const int quad = lane >> 4;
  const int m0 = wv * 32;
  const int m1 = wv * 32 + 16;
  const int j = j0 + ((units == 16) ? lr : (lr & 7));

  const float bI = bias[layer * G4_ + 0 * H_ + j];
  const float bF = bias[layer * G4_ + 1 * H_ + j];
  const float bG = bias[layer * G4_ + 2 * H_ + j];
  const float bO = bias[layer * G4_ + 3 * H_ + j];

  float cst[2][4] = {{0.f, 0.f, 0.f, 0.f}, {0.f, 0.f, 0.f, 0.f}};

  for (int t = 0; t < T_; ++t) {
    const int s = layer + t;
    const int pprev = (s - 1) & (NP_ - 1);
    const int pcur = s & (NP_ - 1);
    const _Float16* hown = hbuf + (size_t)(layer * NP_ + pprev) * B_ * H_;
    _Float16* hout = hbuf + (size_t)(layer * NP_ + pcur) * B_ * H_;

    // ---- epoch gate: ONE L2 invalidate per XCD per epoch (leader election).
    // Stale parity lines in this XCD's L2 date from epoch s-4 readers; leader
    // fences of epochs s-3..s-1 removed them (skew < 4 enforced by the s-3
    // anti-dep + s-1 own-h waits). CU-private L1 staleness: sc0 on h loads.
    if (threadIdx.x == 0) {
      if (__hip_atomic_fetch_add(&tick[xcc * 128 + s], 1, __ATOMIC_RELAXED,
                                 __HIP_MEMORY_SCOPE_AGENT) == 0) {
        __builtin_amdgcn_fence(__ATOMIC_ACQUIRE, "agent");   // inv L1+L2
        __hip_atomic_store(&leadDone[xcc * 128 + s], 1, __ATOMIC_RELEASE,
                           __HIP_MEMORY_SCOPE_AGENT);
      }
    }
    if (lane == 0) {
      int spin = 0;
      while (__hip_atomic_load(&leadDone[xcc * 128 + s], __ATOMIC_RELAXED,
                               __HIP_MEMORY_SCOPE_AGENT) == 0) {
        __builtin_amdgcn_s_sleep(1);
        if (++spin > 2000000) break;
      }
    }

    floatx4 acc0[2][4];
    floatx4 acc2[2][2];

    if (layer == 0) {
      // x-phase: x0 is constant -> no wait; cacheable
#pragma unroll
      for (int a = 0; a < 2; ++a)
#pragma unroll
        for (int b = 0; b < 4; ++b) acc0[a][b] = (floatx4){0.f, 0.f, 0.f, 0.f};
      gemm_phase<4, 4, 2, false>(lw, 0, x0 + (size_t)t * XP_, T_ * XP_, m0, lane, acc0);
      // own-h phase: per-wave wait (all waves), no fence, no barrier
      wait_group(flags, s - 1, 0, lane);
      gemm_phase<4, 4, 24, true>(lw, 2, hown, H_, m0, lane, acc0);
    } else {
      // x-phase: per-wave wait on producer (l-1, s-1); no fence, no barrier
      wait_group(flags, s - 1, layer - 1, lane);
#pragma unroll
      for (int a = 0; a < 2; ++a)
#pragma unroll
        for (int b = 0; b < 2; ++b) acc2[a][b] = (floatx4){0.f, 0.f, 0.f, 0.f};
      const _Float16* xsrc = hbuf + (size_t)((layer - 1) * NP_ + pprev) * B_ * H_;
      gemm_phase<2, 5, 24, true>(lw, 0, xsrc, H_, m0, lane, acc2);
      // own-h phase: per-wave wait, hidden behind the x-phase GEMM
      wait_group(flags, s - 1, layer, lane);
      gemm_phase<2, 5, 24, true>(lw, 24, hown, H_, m0, lane, acc2);
    }

    // anti-dep (relaxed by 4-parity buffering): (l+1) must be done READING
    // parity (s&3) -- its last read of it was at step s-3. Own-layer readers
    // of that parity are covered by the s-1 own-h wait.
    wait_group(flags, s - 3, layer + 1, lane);

    if (layer == 0) {
#pragma unroll
      for (int mt = 0; mt < 2; ++mt)
#pragma unroll
        for (int r = 0; r < 4; ++r) {
          float iv = acc0[mt][0][r] + bI;
          float fv = acc0[mt][1][r] + bF;
          float gv = acc0[mt][2][r] + bG;
          float ov = acc0[mt][3][r] + bO;
          float cn = sigm(fv) * cst[mt][r] + sigm(iv) * tanh_f(gv);
          cst[mt][r] = cn;
          int m = (mt ? m1 : m0) + quad * 4 + r;
          hout[(size_t)m * H_ + j] = (_Float16)(sigm(ov) * tanh_f(cn));
        }
    } else {
      // tile0 cols: i,f (units 0..7); tile1: g,o. xor-8 colocates the 4 gates.
#pragma unroll
      for (int mt = 0; mt < 2; ++mt)
#pragma unroll
        for (int r = 0; r < 4; ++r) {
          float t0 = acc2[mt][0][r], t1 = acc2[mt][1][r];
          float p0 = __shfl_xor(t0, 8, 64);
          float p1 = __shfl_xor(t1, 8, 64);
          bool lo = (lr < 8);
          float iv = (lo ? t0 : p0) + bI;
          float fv = (lo ? p0 : t0) + bF;
          float gv = (lo ? t1 : p1) + bG;
          float ov = (lo ? p1 : t1) + bO;
          float cn = sigm(fv) * cst[mt][r] + sigm(iv) * tanh_f(gv);
          cst[mt][r] = cn;
          if (lo) {
            int m = (mt ? m1 : m0) + quad * 4 + r;
            hout[(size_t)m * H_ + j] = (_Float16)(sigm(ov) * tanh_f(cn));
          }
        }
    }

    __syncthreads();   // drains vmcnt (all waves' stores) before release
    if (threadIdx.x == 0)
      __hip_atomic_store(&flags[(s * 3 + layer) * 96 + tile], 1, __ATOMIC_RELEASE,
                         __HIP_MEMORY_SCOPE_AGENT);
  }
}

// ---------------- projection + normalize ----------------
__global__ void dvec_kernel(const _Float16* __restrict__ hlast, const float* __restrict__ Wproj,
                            const float* __restrict__ bproj, float* __restrict__ d3) {
  const int m = blockIdx.x;
  const int d = threadIdx.x;
  const _Float16* h = hlast + (size_t)m * H_;
  const float* w = Wproj + (size_t)d * H_;
  float acc = bproj[d];
  for (int k = 0; k < H_; k++) acc += (float)h[k] * w[k];
  __shared__ float red[256];
  red[d] = acc * acc;
  __syncthreads();
  for (int off = 128; off > 0; off >>= 1) {
    if (d < off) red[d] += red[d + off];
    __syncthreads();
  }
  float nrm = sqrtf(red[0]);
  d3[(size_t)m * D_ + d] = acc / nrm;
}

// ---------------- GE2E ----------------
__device__ float block_reduce_sum(float x, float* red) {
  const int d = threadIdx.x;
  red[d] = x;
  __syncthreads();
  for (int off = 128; off > 0; off >>= 1) {
    if (d < off) red[d] += red[d + off];
    __syncthreads();
  }
  float r = red[0];
  __syncthreads();
  return r;
}

__global__ void cent_kernel(const float* __restrict__ d3, float* __restrict__ cent,
                            float* __restrict__ ncent) {
  const int sIdx = blockIdx.x;
  const int d = threadIdx.x;
  float acc = 0.f;
  for (int u = 0; u < U_; u++) acc += d3[((size_t)sIdx * U_ + u) * D_ + d];
  acc *= (1.f / U_);
  cent[sIdx * D_ + d] = acc;
  __shared__ float red[256];
  float n2 = block_reduce_sum(acc * acc, red);
  if (d == 0) ncent[sIdx] = fmaxf(sqrtf(n2), 1e-8f);
}

__global__ void ge2e_kernel(const float* __restrict__ d3, const float* __restrict__ cent,
                            const float* __restrict__ ncent, const float* __restrict__ loss_w,
                            const float* __restrict__ loss_b, float* __restrict__ accums) {
  const int p = blockIdx.x;
  const int sIdx = p / U_;
  const int d = threadIdx.x;
  __shared__ float red[256];
  __shared__ float sims[S_];

  const float v = d3[(size_t)p * D_ + d];
  const float cs = cent[sIdx * D_ + d];
  const float pc = (cs * U_ - v) * (1.f / (U_ - 1));

  float nv2 = block_reduce_sum(v * v, red);
  float npc2 = block_reduce_sum(pc * pc, red);
  float dotp = block_reduce_sum(v * pc, red);

  const float w = loss_w[0], b = loss_b[0];
  const float na = fmaxf(sqrtf(nv2), 1e-6f);
  const float npc = fmaxf(sqrtf(npc2), 1e-6f);
  const float pos_sim = w * (dotp / (na * npc)) + b;
  const float nd = fmaxf(sqrtf(nv2), 1e-8f);

  for (int k = 0; k < S_; k++) {
    float dk = block_reduce_sum(v * cent[k * D_ + d], red);
    if (d == 0) sims[k] = w * (dk / (nd * ncent[k])) + b;
  }
  __syncthreads();
  if (d == 0) {
    float mx = -1e30f;
    for (int k = 0; k < S_; k++)
      if (k != sIdx) mx = fmaxf(mx, sims[k]);
    float se = 0.f, sn = 0.f;
    for (int k = 0; k < S_; k++)
      if (k != sIdx) { se += expf(sims[k] - mx); sn += sims[k]; }
    float lse = mx + logf(se);
    atomicAdd(&accums[0], -pos_sim + lse);
    atomicAdd(&accums[1], pos_sim);
    atomicAdd(&accums[2], sn);
  }
}

__global__ void finalize_kernel(const float* __restrict__ accums, float* __restrict__ out) {
  if (threadIdx.x == 0) {
    out[0] = accums[0] / (float)(S_ * U_);
    out[1] = accums[1] / (float)(S_ * U_);
    out[2] = accums[2] / (float)(S_ * U_ * (S_ - 1));
  }
}

// ---------------- launch ----------------
extern "C" void kernel_launch(void* const* d_in, const int* in_sizes, int n_in,
                              void* d_out, int out_size, void* d_ws, size_t ws_size,
                              hipStream_t stream) {
  const float* mel = (const float*)d_in[0];
  const float* Wih[3] = {(const float*)d_in[1], (const float*)d_in[5], (const float*)d_in[9]};
  const float* Whh[3] = {(const float*)d_in[2], (const float*)d_in[6], (const float*)d_in[10]};
  const float* bih[3] = {(const float*)d_in[3], (const float*)d_in[7], (const float*)d_in[11]};
  const float* bhh[3] = {(const float*)d_in[4], (const float*)d_in[8], (const float*)d_in[12]};
  const float* Wproj = (const float*)d_in[13];
  const float* bproj = (const float*)d_in[14];
  const float* loss_w = (const float*)d_in[15];
  const float* loss_b = (const float*)d_in[16];
  float* out = (float*)d_out;

  char* ws = (char*)d_ws;
  size_t off = 0;
  auto alloc = [&](size_t bytes) -> void* {
    void* p = ws + off;
    off = (off + bytes + 255) & ~(size_t)255;
    return p;
  };
  _Float16* x0   = (_Float16*)alloc((size_t)B_ * T_ * XP_ * 2);
  _Float16* Wc0  = (_Float16*)alloc((size_t)G4_ * K0_ * 2);
  _Float16* Wc1  = (_Float16*)alloc((size_t)G4_ * K12_ * 2);
  _Float16* Wc2  = (_Float16*)alloc((size_t)G4_ * K12_ * 2);
  float*    bias = (float*)alloc((size_t)3 * G4_ * 4);
  _Float16* hbuf = (_Float16*)alloc((size_t)3 * NP_ * B_ * H_ * 2);
  float*    d3   = (float*)alloc((size_t)B_ * D_ * 4);
  float*    cent = (float*)alloc((size_t)S_ * D_ * 4);
  float*    ncent = (float*)alloc((size_t)S_ * 4);
  float*    accums = (float*)alloc(64);
  int*      flags = (int*)alloc((size_t)(T_ + 3) * 3 * 96 * 4);
  int*      tick  = (int*)alloc((size_t)8 * 128 * 4);
  int*      lead  = (int*)alloc((size_t)8 * 128 * 4);

  hipMemsetAsync(hbuf, 0, (size_t)3 * NP_ * B_ * H_ * 2, stream);
  hipMemsetAsync(accums, 0, 64, stream);
  hipMemsetAsync(flags, 0, (size_t)(T_ + 3) * 3 * 96 * 4, stream);
  hipMemsetAsync(tick, 0, (size_t)8 * 128 * 4, stream);
  hipMemsetAsync(lead, 0, (size_t)8 * 128 * 4, stream);

  prep_x0<<<(B_ * T_ * XP_ + 255) / 256, 256, 0, stream>>>(mel, x0);
  prep_w0<<<(G4_ * K0_ + 255) / 256, 256, 0, stream>>>(Wih[0], Whh[0], Wc0);
  prep_w12<<<(G4_ * K12_ + 255) / 256, 256, 0, stream>>>(Wih[1], Whh[1], Wc1);
  prep_w12<<<(G4_ * K12_ + 255) / 256, 256, 0, stream>>>(Wih[2], Whh[2], Wc2);
  for (int l = 0; l < 3; l++)
    prep_bias<<<(G4_ + 255) / 256, 256, 0, stream>>>(bih[l], bhh[l], bias + l * G4_);

  hipFuncSetAttribute((const void*)lstm_persist,
                      hipFuncAttributeMaxDynamicSharedMemorySize, SMEM_BYTES);
  void* kargs[] = {(void*)&x0, (void*)&Wc0, (void*)&Wc1, (void*)&Wc2,
                   (void*)&bias, (void*)&hbuf, (void*)&flags, (void*)&tick,
                   (void*)&lead};
  hipLaunchCooperativeKernel((const void*)lstm_persist, dim3(NBLK), dim3(640),
                             kargs, SMEM_BYTES, stream);

  // layer-2 final h: s = 2 + 119 = 121 -> parity 121 & 3 = 1
  const _Float16* hlast = hbuf + (size_t)(2 * NP_ + 1) * B_ * H_;
  dvec_kernel<<<B_, 256, 0, stream>>>(hlast, Wproj, bproj, d3);
  cent_kernel<<<S_, 256, 0, stream>>>(d3, cent, ncent);
  ge2e_kernel<<<B_, 256, 0, stream>>>(d3, cent, ncent, loss_w, loss_b, accums);
  finalize_kernel<<<1, 64, 0, stream>>>(accums, out);
}